// Round 7
// baseline (440.546 us; speedup 1.0000x reference)
//
#include <hip/hip_runtime.h>
#include <math.h>

#define Bc 4
#define Nc 6
#define Dc 59
#define FHc 16
#define FWc 44
#define Cc 64
#define OCc 123   // D + OUT_C
#define NXc 128
#define NYc 128
#define NPIX (Bc*Nc*FHc*FWc)      // 16896
#define PIXPERB (Nc*FHc*FWc)      // 4224
#define NVOX (Bc*NXc*NYc)         // 65536
#define MAXREC (NPIX*(2*Dc))      // 1,993,728 hard upper bound (every point split)
#define CHREC 128                 // records per wave in gather

// ---------------- workspace layout (bytes) ----------------
#define WS_ACC      ((size_t)0)                    // 16,777,216  f32 acc[65536][64]
#define WS_CTX      ((size_t)16777216)             // +4,325,376  f32 ctxg[16896][64]
#define WS_CNT      ((size_t)21102592)             // +262,144    u32 cnt[65536]
#define WS_WOFF     ((size_t)21364736)             // +262,144    u32 watomic[65536]
#define WS_BSUM     ((size_t)21626880)             // +1,024      u32 bsum[256]
#define WS_BEXC     ((size_t)21627904)             // +1,024      u32 bexc[256]
#define WS_TOTAL    ((size_t)21628928)             // +256        u32 totalCnt
#define WS_RECBUF   ((size_t)21629184)             // +15,949,824 u64 recbuf[MAXREC]
#define WS_SORTED   ((size_t)37579008)             // +15,949,824 u64 sorted[MAXREC]
#define WS_NEED     ((size_t)53528832)
#define WS_ZERO_BYTES ((size_t)21629184)           // acc..totalCnt zeroed each launch

// c + (-a)*b : plain (mul+add) or fused, per variant
template<bool FMA>
__device__ __forceinline__ float mulsub(float a, float b, float c) {
    if (FMA) return __fmaf_rn(-a, b, c);
    return __fadd_rn(c, __fmul_rn(-a, b));
}

// numpy.linalg.inv mirror: LAPACK sgesv on the C-order buffer seen as Fortran,
// i.e. factorizes A^T (inv(A) = inv(A^T)^T). sgetf2+sgetrs, strict f32.
template<bool FMA>
__device__ __forceinline__ void lu_inv3x3T(const float* __restrict__ m, float* __restrict__ o) {
    float A[3][3] = {{m[0],m[3],m[6]},{m[1],m[4],m[7]},{m[2],m[5],m[8]}};  // A^T
    int piv0, piv1;
    {
        float a0=fabsf(A[0][0]), a1=fabsf(A[1][0]), a2=fabsf(A[2][0]);
        int p = 0; float mx = a0;
        if (a1 > mx) { mx = a1; p = 1; }
        if (a2 > mx) { mx = a2; p = 2; }
        piv0 = p;
        if (p != 0) { for (int k=0;k<3;++k){ float t=A[0][k]; A[0][k]=A[p][k]; A[p][k]=t; } }
        const float d = __fdiv_rn(1.0f, A[0][0]);
        A[1][0] = __fmul_rn(A[1][0], d);
        A[2][0] = __fmul_rn(A[2][0], d);
        #pragma unroll
        for (int i=1;i<3;++i)
            #pragma unroll
            for (int j=1;j<3;++j)
                A[i][j] = mulsub<FMA>(A[i][0], A[0][j], A[i][j]);
    }
    {
        float a1=fabsf(A[1][1]), a2=fabsf(A[2][1]);
        int p = (a2 > a1) ? 2 : 1;
        piv1 = p;
        if (p != 1) { for (int k=0;k<3;++k){ float t=A[1][k]; A[1][k]=A[p][k]; A[p][k]=t; } }
        const float d = __fdiv_rn(1.0f, A[1][1]);
        A[2][1] = __fmul_rn(A[2][1], d);
        A[2][2] = mulsub<FMA>(A[2][1], A[1][2], A[2][2]);
    }
    float B[3][3] = {{1.f,0.f,0.f},{0.f,1.f,0.f},{0.f,0.f,1.f}};
    if (piv0 != 0) { for (int k=0;k<3;++k){ float t=B[0][k]; B[0][k]=B[piv0][k]; B[piv0][k]=t; } }
    if (piv1 != 1) { for (int k=0;k<3;++k){ float t=B[1][k]; B[1][k]=B[piv1][k]; B[piv1][k]=t; } }
    #pragma unroll
    for (int j=0;j<3;++j) {
        B[1][j] = mulsub<FMA>(A[1][0], B[0][j], B[1][j]);
        B[2][j] = mulsub<FMA>(A[2][0], B[0][j], B[2][j]);
        B[2][j] = mulsub<FMA>(A[2][1], B[1][j], B[2][j]);
        B[2][j] = __fdiv_rn(B[2][j], A[2][2]);
        B[0][j] = mulsub<FMA>(A[0][2], B[2][j], B[0][j]);
        B[1][j] = mulsub<FMA>(A[1][2], B[2][j], B[1][j]);
        B[1][j] = __fdiv_rn(B[1][j], A[1][1]);
        B[0][j] = mulsub<FMA>(A[0][1], B[1][j], B[0][j]);
        B[0][j] = __fdiv_rn(B[0][j], A[0][0]);
    }
    o[0]=B[0][0]; o[1]=B[1][0]; o[2]=B[2][0];
    o[3]=B[0][1]; o[4]=B[1][1]; o[5]=B[2][1];
    o[6]=B[0][2]; o[7]=B[1][2]; o[8]=B[2][2];
}

template<bool FMA>
__device__ __forceinline__ float dot3(float a0,float a1,float a2,float b0,float b1,float b2){
    if (FMA) return __fmaf_rn(a2,b2, __fmaf_rn(a1,b1, __fmul_rn(a0,b0)));
    return __fadd_rn(__fadd_rn(__fmul_rn(a0,b0), __fmul_rn(a1,b1)), __fmul_rn(a2,b2));
}

template<bool FMA>
__device__ __forceinline__ int geom_voxel(
    const float* __restrict__ pr, const float* __restrict__ pt,
    const float* __restrict__ ro, const float* __restrict__ it,
    const float* __restrict__ tr, float u, float v, float dval, int b)
{
    float PRi[9], INi[9], CM[9];
    lu_inv3x3T<FMA>(pr, PRi);
    lu_inv3x3T<FMA>(it, INi);
    #pragma unroll
    for (int r2 = 0; r2 < 3; ++r2)
        #pragma unroll
        for (int c2 = 0; c2 < 3; ++c2)
            CM[r2*3+c2] = dot3<true>(ro[r2*3+0], ro[r2*3+1], ro[r2*3+2],
                                     INi[0*3+c2], INi[1*3+c2], INi[2*3+c2]);
    const float p0 = __fsub_rn(u,    pt[0]);
    const float p1 = __fsub_rn(v,    pt[1]);
    const float p2 = __fsub_rn(dval, pt[2]);
    const float q0 = dot3<FMA>(PRi[0],PRi[1],PRi[2], p0,p1,p2);
    const float q1 = dot3<FMA>(PRi[3],PRi[4],PRi[5], p0,p1,p2);
    const float q2 = dot3<FMA>(PRi[6],PRi[7],PRi[8], p0,p1,p2);
    const float r0 = __fmul_rn(q0, q2);
    const float r1 = __fmul_rn(q1, q2);
    const float s0 = __fadd_rn(dot3<FMA>(CM[0],CM[1],CM[2], r0,r1,q2), tr[0]);
    const float s1 = __fadd_rn(dot3<FMA>(CM[3],CM[4],CM[5], r0,r1,q2), tr[1]);
    const float s2 = __fadd_rn(dot3<FMA>(CM[6],CM[7],CM[8], r0,r1,q2), tr[2]);
    const float CX  = -51.200000762939453f;
    const float DXf =  0.80000001192092896f;
    const float gx = __fdiv_rn(__fsub_rn(s0, CX), DXf);
    const float gy = __fdiv_rn(__fsub_rn(s1, CX), DXf);
    const float gz = __fdiv_rn(__fsub_rn(s2, -10.0f), 20.0f);
    const bool kept = (gx > -1.0f) && (gx < 128.0f) &&
                      (gy > -1.0f) && (gy < 128.0f) &&
                      (gz > -1.0f) && (gz < 1.0f);
    return kept ? (b*(NXc*NYc) + ((int)gy)*NXc + (int)gx) : -1;
}

__device__ __forceinline__ unsigned long long mk_rec(int vox, int pix, float w) {
    unsigned meta = ((unsigned)(vox & 16383) << 15) | (unsigned)pix;
    return ((unsigned long long)__float_as_uint(w) << 32) | meta;
}

// ---- K1: per-pixel compute, record emission + histogram (no fp32 scatter) ----
__global__ __launch_bounds__(128) void lss_pixel(
    const float* __restrict__ x, const float* __restrict__ rots,
    const float* __restrict__ trans, const float* __restrict__ intrins,
    const float* __restrict__ post_rots, const float* __restrict__ post_trans,
    const float* __restrict__ wd, const float* __restrict__ bd,
    float* __restrict__ ctxg, unsigned* __restrict__ cnt,
    unsigned* __restrict__ totalCnt, unsigned long long* __restrict__ recbuf)
{
    const int pix = blockIdx.x;
    const int wi = pix % FWc;
    const int hi = (pix / FWc) % FHc;
    const int n  = (pix / (FWc * FHc)) % Nc;
    const int b  =  pix / (FWc * FHc * Nc);
    const int t = threadIdx.x;

    __shared__ float xs[Cc];
    __shared__ float yv[OCc];
    __shared__ int   voxA[Dc];
    __shared__ int   voxB[Dc];

    if (t < Cc)
        xs[t] = x[(((size_t)(b*Nc + n)*Cc + t)*FHc + hi)*FWc + wi];
    __syncthreads();

    if (t < OCc) {
        const float* wr = wd + t*Cc;
        float a = 0.0f;
        #pragma unroll
        for (int c2 = 0; c2 < Cc; ++c2)
            a = __fmaf_rn(wr[c2], xs[c2], a);
        yv[t] = __fadd_rn(a, bd[t]);
    }
    __syncthreads();

    float depv = 0.0f;
    if (t < 64) {
        float v = (t < Dc) ? yv[t] : -INFINITY;
        float m = v;
        #pragma unroll
        for (int off = 32; off; off >>= 1) m = fmaxf(m, __shfl_xor(m, off));
        float e = (t < Dc) ? expf(__fsub_rn(v, m)) : 0.0f;
        float s = e;
        #pragma unroll
        for (int off = 32; off; off >>= 1) s = __fadd_rn(s, __shfl_xor(s, off));
        if (t < Dc) depv = __fdiv_rn(e, s);
    } else {
        const int t2 = t - 64;
        if (t2 < Cc) ctxg[(size_t)pix*64 + t2] = yv[Dc + t2];   // context to global
        if (t2 < Dc) {
            const int cam = b*Nc + n;
            const float* pr = post_rots  + cam*9;
            const float* pt = post_trans + cam*3;
            const float* ro = rots       + cam*9;
            const float* it = intrins    + cam*9;
            const float* tr = trans      + cam*3;
            const float u    = (float)(wi * (703.0 / 43.0));
            const float v    = (float)(hi * 17.0);
            const float dval = (float)(1 + t2);
            voxA[t2] = geom_voxel<true >(pr, pt, ro, it, tr, u, v, dval, b);
            voxB[t2] = geom_voxel<false>(pr, pt, ro, it, tr, u, v, dval, b);
        }
    }
    __syncthreads();

    // wave 0: emit records (agree -> one full-weight; disagree -> two half-weight)
    if (t < 64) {
        int vA = (t < Dc) ? voxA[t] : -1;
        int vB = (t < Dc) ? voxB[t] : -1;
        unsigned ne = 0;
        unsigned long long r0 = 0, r1 = 0;
        int hv0 = -1, hv1 = -1;
        if (t < Dc) {
            if (vA == vB) {
                if (vA >= 0) { r0 = mk_rec(vA, pix, depv); hv0 = vA; ne = 1; }
            } else {
                const float hw = __fmul_rn(depv, 0.5f);
                if (vA >= 0) { r0 = mk_rec(vA, pix, hw); hv0 = vA; ne = 1; }
                if (vB >= 0) {
                    if (ne) { r1 = mk_rec(vB, pix, hw); hv1 = vB; ne = 2; }
                    else    { r0 = mk_rec(vB, pix, hw); hv0 = vB; ne = 1; }
                }
            }
        }
        // wave-exclusive scan of ne (all 64 lanes participate)
        unsigned pre = ne;
        #pragma unroll
        for (int off = 1; off < 64; off <<= 1) {
            unsigned vv = __shfl_up(pre, off);
            if (t >= off) pre += vv;
        }
        unsigned tot = __shfl(pre, 63);
        unsigned exc = pre - ne;
        unsigned base = 0;
        if (t == 63) base = atomicAdd(totalCnt, tot);
        base = __shfl(base, 63);
        if (ne >= 1) { recbuf[base + exc]     = r0; atomicAdd(&cnt[hv0], 1u); }
        if (ne == 2) { recbuf[base + exc + 1] = r1; atomicAdd(&cnt[hv1], 1u); }
    }
}

// ---- K2a/K2b/K2c: 65536-bin exclusive scan -> watomic ----
__global__ __launch_bounds__(256) void scan_block_sum(const unsigned* __restrict__ cnt,
                                                      unsigned* __restrict__ bsum) {
    __shared__ unsigned s[256];
    const int tid = threadIdx.x;
    s[tid] = cnt[blockIdx.x*256 + tid];
    __syncthreads();
    for (int off = 128; off; off >>= 1) {
        if (tid < off) s[tid] += s[tid + off];
        __syncthreads();
    }
    if (tid == 0) bsum[blockIdx.x] = s[0];
}

__global__ __launch_bounds__(256) void scan_top(const unsigned* __restrict__ bsum,
                                                unsigned* __restrict__ bexc) {
    __shared__ unsigned s[256];
    const int tid = threadIdx.x;
    const unsigned v = bsum[tid];
    s[tid] = v;
    __syncthreads();
    for (int off = 1; off < 256; off <<= 1) {
        unsigned tv = (tid >= off) ? s[tid - off] : 0u;
        __syncthreads();
        s[tid] += tv;
        __syncthreads();
    }
    bexc[tid] = s[tid] - v;   // exclusive
}

__global__ __launch_bounds__(256) void scan_apply(const unsigned* __restrict__ cnt,
                                                  const unsigned* __restrict__ bexc,
                                                  unsigned* __restrict__ watomic) {
    __shared__ unsigned s[256];
    const int tid = threadIdx.x;
    const int i = blockIdx.x*256 + tid;
    const unsigned v = cnt[i];
    s[tid] = v;
    __syncthreads();
    for (int off = 1; off < 256; off <<= 1) {
        unsigned tv = (tid >= off) ? s[tid - off] : 0u;
        __syncthreads();
        s[tid] += tv;
        __syncthreads();
    }
    watomic[i] = bexc[blockIdx.x] + (s[tid] - v);   // global exclusive offset
}

// ---- K3: scatter records into voxel-sorted order ----
__global__ __launch_bounds__(256) void sort_scatter(
    const unsigned long long* __restrict__ recbuf,
    const unsigned* __restrict__ totalCnt,
    unsigned* __restrict__ watomic,
    unsigned long long* __restrict__ sorted)
{
    const unsigned i = blockIdx.x*256u + threadIdx.x;
    const unsigned total = *totalCnt;
    if (i >= total) return;
    const unsigned long long rec = recbuf[i];
    const unsigned meta = (unsigned)rec;
    const unsigned pix  = meta & 0x7FFFu;
    const unsigned cell = meta >> 15;
    const unsigned vox  = (pix / (unsigned)PIXPERB) * 16384u + cell;
    const unsigned pos  = atomicAdd(&watomic[vox], 1u);
    sorted[pos] = rec;
}

// ---- K4: grouped gather; middle runs store non-atomically ----
__global__ __launch_bounds__(256) void gather(
    const unsigned long long* __restrict__ sorted,
    const unsigned* __restrict__ totalCnt,
    const float* __restrict__ ctxg,
    float* __restrict__ acc)
{
    const unsigned lane = threadIdx.x & 63u;
    const unsigned wave = (blockIdx.x << 2) | (threadIdx.x >> 6);
    const unsigned total = *totalCnt;
    unsigned r = wave * (unsigned)CHREC;
    if (r >= total) return;
    const unsigned c0 = r;
    const unsigned end = (c0 + CHREC < total) ? (c0 + CHREC) : total;
    int curVox = -1;
    unsigned runStart = c0;
    float accv = 0.0f;
    for (; r < end; ++r) {
        const unsigned long long rec = sorted[r];
        const unsigned meta = (unsigned)rec;
        const float w = __uint_as_float((unsigned)(rec >> 32));
        const unsigned pix  = meta & 0x7FFFu;
        const unsigned cell = meta >> 15;
        const int vox = (int)((pix / (unsigned)PIXPERB) * 16384u + cell);
        if (vox != curVox) {
            if (curVox >= 0) {
                if (runStart == c0) atomicAdd(&acc[((size_t)curVox << 6) + lane], accv);
                else                acc[((size_t)curVox << 6) + lane] = accv;  // exclusive voxel
            }
            curVox = vox; runStart = r; accv = 0.0f;
        }
        accv = __fadd_rn(accv, __fmul_rn(w, ctxg[((size_t)pix << 6) + lane]));
    }
    if (curVox >= 0) atomicAdd(&acc[((size_t)curVox << 6) + lane], accv);  // boundary run
}

// ---- fallback: R6 direct-atomic kernel (used only if ws too small) ----
__global__ __launch_bounds__(128) void lss_main_atomic(
    const float* __restrict__ x, const float* __restrict__ rots,
    const float* __restrict__ trans, const float* __restrict__ intrins,
    const float* __restrict__ post_rots, const float* __restrict__ post_trans,
    const float* __restrict__ wd, const float* __restrict__ bd,
    float* __restrict__ acc)
{
    const int pix = blockIdx.x;
    const int wi = pix % FWc;
    const int hi = (pix / FWc) % FHc;
    const int n  = (pix / (FWc * FHc)) % Nc;
    const int b  =  pix / (FWc * FHc * Nc);
    const int t = threadIdx.x;

    __shared__ float xs[Cc];
    __shared__ float yv[OCc];
    __shared__ float dep[Dc];
    __shared__ float ctx[Cc];
    __shared__ int   voxA[Dc];
    __shared__ int   voxB[Dc];

    if (t < Cc)
        xs[t] = x[(((size_t)(b*Nc + n)*Cc + t)*FHc + hi)*FWc + wi];
    __syncthreads();

    if (t < OCc) {
        const float* wr = wd + t*Cc;
        float a = 0.0f;
        #pragma unroll
        for (int c2 = 0; c2 < Cc; ++c2)
            a = __fmaf_rn(wr[c2], xs[c2], a);
        yv[t] = __fadd_rn(a, bd[t]);
    }
    __syncthreads();

    if (t < 64) {
        float v = (t < Dc) ? yv[t] : -INFINITY;
        float m = v;
        #pragma unroll
        for (int off = 32; off; off >>= 1) m = fmaxf(m, __shfl_xor(m, off));
        float e = (t < Dc) ? expf(__fsub_rn(v, m)) : 0.0f;
        float s = e;
        #pragma unroll
        for (int off = 32; off; off >>= 1) s = __fadd_rn(s, __shfl_xor(s, off));
        if (t < Dc) dep[t] = __fdiv_rn(e, s);
    } else {
        const int t2 = t - 64;
        if (t2 < Cc) ctx[t2] = yv[Dc + t2];
        if (t2 < Dc) {
            const int cam = b*Nc + n;
            const float u    = (float)(wi * (703.0 / 43.0));
            const float v    = (float)(hi * 17.0);
            const float dval = (float)(1 + t2);
            voxA[t2] = geom_voxel<true >(post_rots+cam*9, post_trans+cam*3, rots+cam*9,
                                         intrins+cam*9, trans+cam*3, u, v, dval, b);
            voxB[t2] = geom_voxel<false>(post_rots+cam*9, post_trans+cam*3, rots+cam*9,
                                         intrins+cam*9, trans+cam*3, u, v, dval, b);
        }
    }
    __syncthreads();

    const int ch = t & 63;
    const float cv = ctx[ch];
    for (int d2 = (t >> 6); d2 < Dc; d2 += 2) {
        const int vA = voxA[d2];
        const int vB = voxB[d2];
        const float w = __fmul_rn(dep[d2], cv);
        if (vA == vB) {
            if (vA >= 0) atomicAdd(&acc[(size_t)vA*64 + ch], w);
        } else {
            const float hw = __fmul_rn(w, 0.5f);
            if (vA >= 0) atomicAdd(&acc[(size_t)vA*64 + ch], hw);
            if (vB >= 0) atomicAdd(&acc[(size_t)vB*64 + ch], hw);
        }
    }
}

// (b, pix, ch) -> (b, ch, pix) transpose, 64x64 tiles
__global__ __launch_bounds__(256) void lss_transpose(
    const float* __restrict__ acc, float* __restrict__ out)
{
    __shared__ float tile[64][65];
    const int blk = blockIdx.x;
    const int b = blk >> 8;
    const int pixbase = (blk & 255) * 64;
    const float* src = acc + ((size_t)b*16384 + pixbase)*64;
    const int t = threadIdx.x;
    #pragma unroll
    for (int i = 0; i < 16; ++i) {
        const int e = i*256 + t;
        tile[e & 63][e >> 6] = src[e];
    }
    __syncthreads();
    float* dst = out + (size_t)b*64*16384 + pixbase;
    #pragma unroll
    for (int i = 0; i < 16; ++i) {
        const int e = i*256 + t;
        const int c = e >> 6, p = e & 63;
        dst[(size_t)c*16384 + p] = tile[c][p];
    }
}

extern "C" void kernel_launch(void* const* d_in, const int* in_sizes, int n_in,
                              void* d_out, int out_size, void* d_ws, size_t ws_size,
                              hipStream_t stream) {
    const float* x          = (const float*)d_in[0];
    const float* rots       = (const float*)d_in[1];
    const float* trans      = (const float*)d_in[2];
    const float* intrins    = (const float*)d_in[3];
    const float* post_rots  = (const float*)d_in[4];
    const float* post_trans = (const float*)d_in[5];
    const float* wd         = (const float*)d_in[6];
    const float* bd         = (const float*)d_in[7];
    float* out = (float*)d_out;
    char* ws = (char*)d_ws;

    float*    acc      = (float*)(ws + WS_ACC);
    float*    ctxg     = (float*)(ws + WS_CTX);
    unsigned* cnt      = (unsigned*)(ws + WS_CNT);
    unsigned* watomic  = (unsigned*)(ws + WS_WOFF);
    unsigned* bsum     = (unsigned*)(ws + WS_BSUM);
    unsigned* bexc     = (unsigned*)(ws + WS_BEXC);
    unsigned* totalCnt = (unsigned*)(ws + WS_TOTAL);
    unsigned long long* recbuf = (unsigned long long*)(ws + WS_RECBUF);
    unsigned long long* sorted = (unsigned long long*)(ws + WS_SORTED);

    if (ws_size >= WS_NEED) {
        // zero acc + ctx(overwritten anyway) + cnt + control words in one memset
        hipMemsetAsync(ws, 0, WS_ZERO_BYTES, stream);
        lss_pixel<<<dim3(NPIX), dim3(128), 0, stream>>>(
            x, rots, trans, intrins, post_rots, post_trans, wd, bd,
            ctxg, cnt, totalCnt, recbuf);
        scan_block_sum<<<dim3(256), dim3(256), 0, stream>>>(cnt, bsum);
        scan_top<<<dim3(1), dim3(256), 0, stream>>>(bsum, bexc);
        scan_apply<<<dim3(256), dim3(256), 0, stream>>>(cnt, bexc, watomic);
        sort_scatter<<<dim3((MAXREC + 255)/256), dim3(256), 0, stream>>>(
            recbuf, totalCnt, watomic, sorted);
        gather<<<dim3((MAXREC + 4*CHREC - 1)/(4*CHREC)), dim3(256), 0, stream>>>(
            sorted, totalCnt, ctxg, acc);
    } else {
        hipMemsetAsync(acc, 0, (size_t)NVOX*64*sizeof(float), stream);
        lss_main_atomic<<<dim3(NPIX), dim3(128), 0, stream>>>(
            x, rots, trans, intrins, post_rots, post_trans, wd, bd, acc);
    }
    lss_transpose<<<dim3(Bc*256), dim3(256), 0, stream>>>(acc, out);
}

// Round 8
// 389.623 us; speedup vs baseline: 1.1307x; 1.1307x over previous
//
#include <hip/hip_runtime.h>
#include <math.h>

#define Bc 4
#define Nc 6
#define Dc 59
#define FHc 16
#define FWc 44
#define Cc 64
#define OCc 123   // D + OUT_C
#define NXc 128
#define NYc 128
#define NPIX (Bc*Nc*FHc*FWc)      // 16896
#define NVOX (Bc*NXc*NYc)         // 65536

// ws layout: acc[65536][64] f32 (16 MB), then camMat[24][2][18] f32
#define WS_ACC 0
#define WS_CAM ((size_t)16777216)

// c + (-a)*b : plain (mul+add) or fused, per variant
template<bool FMA>
__device__ __forceinline__ float mulsub(float a, float b, float c) {
    if (FMA) return __fmaf_rn(-a, b, c);
    return __fadd_rn(c, __fmul_rn(-a, b));
}

// numpy.linalg.inv mirror: LAPACK sgesv on the C-order buffer seen as Fortran,
// i.e. factorizes A^T (inv(A) = inv(A^T)^T). sgetf2+sgetrs, strict f32.
template<bool FMA>
__device__ __forceinline__ void lu_inv3x3T(const float* __restrict__ m, float* __restrict__ o) {
    float A[3][3] = {{m[0],m[3],m[6]},{m[1],m[4],m[7]},{m[2],m[5],m[8]}};  // A^T
    int piv0, piv1;
    {
        float a0=fabsf(A[0][0]), a1=fabsf(A[1][0]), a2=fabsf(A[2][0]);
        int p = 0; float mx = a0;
        if (a1 > mx) { mx = a1; p = 1; }
        if (a2 > mx) { mx = a2; p = 2; }
        piv0 = p;
        if (p != 0) { for (int k=0;k<3;++k){ float t=A[0][k]; A[0][k]=A[p][k]; A[p][k]=t; } }
        const float d = __fdiv_rn(1.0f, A[0][0]);
        A[1][0] = __fmul_rn(A[1][0], d);
        A[2][0] = __fmul_rn(A[2][0], d);
        #pragma unroll
        for (int i=1;i<3;++i)
            #pragma unroll
            for (int j=1;j<3;++j)
                A[i][j] = mulsub<FMA>(A[i][0], A[0][j], A[i][j]);
    }
    {
        float a1=fabsf(A[1][1]), a2=fabsf(A[2][1]);
        int p = (a2 > a1) ? 2 : 1;
        piv1 = p;
        if (p != 1) { for (int k=0;k<3;++k){ float t=A[1][k]; A[1][k]=A[p][k]; A[p][k]=t; } }
        const float d = __fdiv_rn(1.0f, A[1][1]);
        A[2][1] = __fmul_rn(A[2][1], d);
        A[2][2] = mulsub<FMA>(A[2][1], A[1][2], A[2][2]);
    }
    float B[3][3] = {{1.f,0.f,0.f},{0.f,1.f,0.f},{0.f,0.f,1.f}};
    if (piv0 != 0) { for (int k=0;k<3;++k){ float t=B[0][k]; B[0][k]=B[piv0][k]; B[piv0][k]=t; } }
    if (piv1 != 1) { for (int k=0;k<3;++k){ float t=B[1][k]; B[1][k]=B[piv1][k]; B[piv1][k]=t; } }
    #pragma unroll
    for (int j=0;j<3;++j) {
        B[1][j] = mulsub<FMA>(A[1][0], B[0][j], B[1][j]);
        B[2][j] = mulsub<FMA>(A[2][0], B[0][j], B[2][j]);
        B[2][j] = mulsub<FMA>(A[2][1], B[1][j], B[2][j]);
        B[2][j] = __fdiv_rn(B[2][j], A[2][2]);
        B[0][j] = mulsub<FMA>(A[0][2], B[2][j], B[0][j]);
        B[1][j] = mulsub<FMA>(A[1][2], B[2][j], B[1][j]);
        B[1][j] = __fdiv_rn(B[1][j], A[1][1]);
        B[0][j] = mulsub<FMA>(A[0][1], B[1][j], B[0][j]);
        B[0][j] = __fdiv_rn(B[0][j], A[0][0]);
    }
    o[0]=B[0][0]; o[1]=B[1][0]; o[2]=B[2][0];
    o[3]=B[0][1]; o[4]=B[1][1]; o[5]=B[2][1];
    o[6]=B[0][2]; o[7]=B[1][2]; o[8]=B[2][2];
}

template<bool FMA>
__device__ __forceinline__ float dot3(float a0,float a1,float a2,float b0,float b1,float b2){
    if (FMA) return __fmaf_rn(a2,b2, __fmaf_rn(a1,b1, __fmul_rn(a0,b0)));
    return __fadd_rn(__fadd_rn(__fmul_rn(a0,b0), __fmul_rn(a1,b1)), __fmul_rn(a2,b2));
}

// ---- K0: per-(camera, variant) matrix precompute: PRi[9] + CM[9] -> camMat ----
__global__ __launch_bounds__(64) void cam_precompute(
    const float* __restrict__ rots, const float* __restrict__ intrins,
    const float* __restrict__ post_rots, float* __restrict__ camMat)
{
    const int t = threadIdx.x;
    if (t >= 48) return;
    const int cam = t >> 1;
    const int var = t & 1;          // 0 = FMA (variant A), 1 = non-FMA (variant B)
    const float* pr = post_rots + cam*9;
    const float* ro = rots      + cam*9;
    const float* it = intrins   + cam*9;
    float PRi[9], INi[9], CM[9];
    if (var == 0) { lu_inv3x3T<true >(pr, PRi); lu_inv3x3T<true >(it, INi); }
    else          { lu_inv3x3T<false>(pr, PRi); lu_inv3x3T<false>(it, INi); }
    // comb = rots @ inv(intrins): BLAS sgemm -> FMA ascending (both variants)
    #pragma unroll
    for (int r2 = 0; r2 < 3; ++r2)
        #pragma unroll
        for (int c2 = 0; c2 < 3; ++c2)
            CM[r2*3+c2] = dot3<true>(ro[r2*3+0], ro[r2*3+1], ro[r2*3+2],
                                     INi[0*3+c2], INi[1*3+c2], INi[2*3+c2]);
    float* dst = camMat + (size_t)(cam*2 + var)*18;
    #pragma unroll
    for (int k = 0; k < 9; ++k) { dst[k] = PRi[k]; dst[9+k] = CM[k]; }
}

// Per-point geometry using precomputed PRi/CM (ops identical to R6 path)
template<bool FMA>
__device__ __forceinline__ int geom_light(
    const float* __restrict__ PRi, const float* __restrict__ CM,
    const float* __restrict__ pt, const float* __restrict__ tr,
    float u, float v, float dval, int b)
{
    const float p0 = __fsub_rn(u,    pt[0]);
    const float p1 = __fsub_rn(v,    pt[1]);
    const float p2 = __fsub_rn(dval, pt[2]);
    const float q0 = dot3<FMA>(PRi[0],PRi[1],PRi[2], p0,p1,p2);
    const float q1 = dot3<FMA>(PRi[3],PRi[4],PRi[5], p0,p1,p2);
    const float q2 = dot3<FMA>(PRi[6],PRi[7],PRi[8], p0,p1,p2);
    const float r0 = __fmul_rn(q0, q2);
    const float r1 = __fmul_rn(q1, q2);
    const float s0 = __fadd_rn(dot3<FMA>(CM[0],CM[1],CM[2], r0,r1,q2), tr[0]);
    const float s1 = __fadd_rn(dot3<FMA>(CM[3],CM[4],CM[5], r0,r1,q2), tr[1]);
    const float s2 = __fadd_rn(dot3<FMA>(CM[6],CM[7],CM[8], r0,r1,q2), tr[2]);
    const float CX  = -51.200000762939453f;  // f32(f32(-50.8) - f32(0.8)/2)
    const float DXf =  0.80000001192092896f; // f32(0.8)
    const float gx = __fdiv_rn(__fsub_rn(s0, CX), DXf);
    const float gy = __fdiv_rn(__fsub_rn(s1, CX), DXf);
    const float gz = __fdiv_rn(__fsub_rn(s2, -10.0f), 20.0f);
    const bool kept = (gx > -1.0f) && (gx < 128.0f) &&
                      (gy > -1.0f) && (gy < 128.0f) &&
                      (gz > -1.0f) && (gz < 1.0f);
    return kept ? (b*(NXc*NYc) + ((int)gy)*NXc + (int)gx) : -1;
}

// ---- K1: one block per pixel; wave0 softmax, wave1 geometry; both scatter ----
__global__ __launch_bounds__(128) void lss_main(
    const float* __restrict__ x, const float* __restrict__ trans,
    const float* __restrict__ post_trans,
    const float* __restrict__ wd, const float* __restrict__ bd,
    const float* __restrict__ camMat, float* __restrict__ acc)
{
    const int pix = blockIdx.x;
    const int wi = pix % FWc;
    const int hi = (pix / FWc) % FHc;
    const int n  = (pix / (FWc * FHc)) % Nc;
    const int b  =  pix / (FWc * FHc * Nc);
    const int t = threadIdx.x;

    __shared__ float xs[Cc];
    __shared__ float yv[OCc];
    __shared__ float dep[Dc];
    __shared__ float ctx[Cc];
    __shared__ int   voxA[Dc];
    __shared__ int   voxB[Dc];

    if (t < Cc)
        xs[t] = x[(((size_t)(b*Nc + n)*Cc + t)*FHc + hi)*FWc + wi];
    __syncthreads();

    // y[o] = (sum_c w[o][c]*x[c]) + b[o]; FMA chain ascending
    if (t < OCc) {
        const float* wr = wd + t*Cc;
        float a = 0.0f;
        #pragma unroll
        for (int c2 = 0; c2 < Cc; ++c2)
            a = __fmaf_rn(wr[c2], xs[c2], a);
        yv[t] = __fadd_rn(a, bd[t]);
    }
    __syncthreads();

    if (t < 64) {
        // wave 0: softmax over yv[0..58], f32
        float v = (t < Dc) ? yv[t] : -INFINITY;
        float m = v;
        #pragma unroll
        for (int off = 32; off; off >>= 1) m = fmaxf(m, __shfl_xor(m, off));
        float e = (t < Dc) ? expf(__fsub_rn(v, m)) : 0.0f;
        float s = e;
        #pragma unroll
        for (int off = 32; off; off >>= 1) s = __fadd_rn(s, __shfl_xor(s, off));
        if (t < Dc) dep[t] = __fdiv_rn(e, s);
    } else {
        // wave 1: context copy + light geometry (precomputed matrices)
        const int t2 = t - 64;
        if (t2 < Cc) ctx[t2] = yv[Dc + t2];
        if (t2 < Dc) {
            const int cam = b*Nc + n;
            const float* pt = post_trans + cam*3;
            const float* tr = trans      + cam*3;
            const float* M0 = camMat + (size_t)(cam*2 + 0)*18;  // FMA variant
            const float* M1 = camMat + (size_t)(cam*2 + 1)*18;  // non-FMA variant
            const float u    = (float)(wi * (703.0 / 43.0));
            const float v    = (float)(hi * 17.0);
            const float dval = (float)(1 + t2);
            voxA[t2] = geom_light<true >(M0, M0+9, pt, tr, u, v, dval, b);
            voxB[t2] = geom_light<false>(M1, M1+9, pt, tr, u, v, dval, b);
        }
    }
    __syncthreads();

    // scatter: agree -> full deposit; disagree (ambiguous vs np) -> 50/50 split
    const int ch = t & 63;
    const float cv = ctx[ch];
    for (int d2 = (t >> 6); d2 < Dc; d2 += 2) {
        const int vA = voxA[d2];
        const int vB = voxB[d2];
        const float w = __fmul_rn(dep[d2], cv);
        if (vA == vB) {
            if (vA >= 0) atomicAdd(&acc[(size_t)vA*64 + ch], w);
        } else {
            const float hw = __fmul_rn(w, 0.5f);
            if (vA >= 0) atomicAdd(&acc[(size_t)vA*64 + ch], hw);
            if (vB >= 0) atomicAdd(&acc[(size_t)vB*64 + ch], hw);
        }
    }
}

// (b, pix, ch) -> (b, ch, pix) transpose, 64x64 tiles
__global__ __launch_bounds__(256) void lss_transpose(
    const float* __restrict__ acc, float* __restrict__ out)
{
    __shared__ float tile[64][65];
    const int blk = blockIdx.x;
    const int b = blk >> 8;
    const int pixbase = (blk & 255) * 64;
    const float* src = acc + ((size_t)b*16384 + pixbase)*64;
    const int t = threadIdx.x;
    #pragma unroll
    for (int i = 0; i < 16; ++i) {
        const int e = i*256 + t;
        tile[e & 63][e >> 6] = src[e];
    }
    __syncthreads();
    float* dst = out + (size_t)b*64*16384 + pixbase;
    #pragma unroll
    for (int i = 0; i < 16; ++i) {
        const int e = i*256 + t;
        const int c = e >> 6, p = e & 63;
        dst[(size_t)c*16384 + p] = tile[c][p];
    }
}

extern "C" void kernel_launch(void* const* d_in, const int* in_sizes, int n_in,
                              void* d_out, int out_size, void* d_ws, size_t ws_size,
                              hipStream_t stream) {
    const float* x          = (const float*)d_in[0];
    const float* rots       = (const float*)d_in[1];
    const float* trans      = (const float*)d_in[2];
    const float* intrins    = (const float*)d_in[3];
    const float* post_rots  = (const float*)d_in[4];
    const float* post_trans = (const float*)d_in[5];
    const float* wd         = (const float*)d_in[6];
    const float* bd         = (const float*)d_in[7];
    float* out = (float*)d_out;
    char* ws = (char*)d_ws;

    float* acc    = (float*)(ws + WS_ACC);
    float* camMat = (float*)(ws + WS_CAM);

    hipMemsetAsync(acc, 0, (size_t)NVOX*64*sizeof(float), stream);
    cam_precompute<<<dim3(1), dim3(64), 0, stream>>>(rots, intrins, post_rots, camMat);
    lss_main<<<dim3(NPIX), dim3(128), 0, stream>>>(
        x, trans, post_trans, wd, bd, camMat, acc);
    lss_transpose<<<dim3(Bc*256), dim3(256), 0, stream>>>(acc, out);
}

// Round 9
// 227.890 us; speedup vs baseline: 1.9331x; 1.7097x over previous
//
#include <hip/hip_runtime.h>
#include <math.h>

#define Bc 4
#define Nc 6
#define Dc 59
#define FHc 16
#define FWc 44
#define Cc 64
#define OCc 123   // D + OUT_C
#define NXc 128
#define NYc 128
#define NVOX (Bc*NXc*NYc)         // 65536
#define NBLK (Bc*Nc*FWc)          // 1056 blocks = (cam, wi)

// ws layout: acc[65536][64] f32 (16 MB), then camMat[24][2][18] f32
#define WS_ACC 0
#define WS_CAM ((size_t)16777216)

template<bool FMA>
__device__ __forceinline__ float mulsub(float a, float b, float c) {
    if (FMA) return __fmaf_rn(-a, b, c);
    return __fadd_rn(c, __fmul_rn(-a, b));
}

// numpy.linalg.inv mirror: LAPACK sgesv on the C-order buffer seen as Fortran,
// i.e. factorizes A^T (inv(A) = inv(A^T)^T). sgetf2+sgetrs, strict f32.
template<bool FMA>
__device__ __forceinline__ void lu_inv3x3T(const float* __restrict__ m, float* __restrict__ o) {
    float A[3][3] = {{m[0],m[3],m[6]},{m[1],m[4],m[7]},{m[2],m[5],m[8]}};  // A^T
    int piv0, piv1;
    {
        float a0=fabsf(A[0][0]), a1=fabsf(A[1][0]), a2=fabsf(A[2][0]);
        int p = 0; float mx = a0;
        if (a1 > mx) { mx = a1; p = 1; }
        if (a2 > mx) { mx = a2; p = 2; }
        piv0 = p;
        if (p != 0) { for (int k=0;k<3;++k){ float t=A[0][k]; A[0][k]=A[p][k]; A[p][k]=t; } }
        const float d = __fdiv_rn(1.0f, A[0][0]);
        A[1][0] = __fmul_rn(A[1][0], d);
        A[2][0] = __fmul_rn(A[2][0], d);
        #pragma unroll
        for (int i=1;i<3;++i)
            #pragma unroll
            for (int j=1;j<3;++j)
                A[i][j] = mulsub<FMA>(A[i][0], A[0][j], A[i][j]);
    }
    {
        float a1=fabsf(A[1][1]), a2=fabsf(A[2][1]);
        int p = (a2 > a1) ? 2 : 1;
        piv1 = p;
        if (p != 1) { for (int k=0;k<3;++k){ float t=A[1][k]; A[1][k]=A[p][k]; A[p][k]=t; } }
        const float d = __fdiv_rn(1.0f, A[1][1]);
        A[2][1] = __fmul_rn(A[2][1], d);
        A[2][2] = mulsub<FMA>(A[2][1], A[1][2], A[2][2]);
    }
    float B[3][3] = {{1.f,0.f,0.f},{0.f,1.f,0.f},{0.f,0.f,1.f}};
    if (piv0 != 0) { for (int k=0;k<3;++k){ float t=B[0][k]; B[0][k]=B[piv0][k]; B[piv0][k]=t; } }
    if (piv1 != 1) { for (int k=0;k<3;++k){ float t=B[1][k]; B[1][k]=B[piv1][k]; B[piv1][k]=t; } }
    #pragma unroll
    for (int j=0;j<3;++j) {
        B[1][j] = mulsub<FMA>(A[1][0], B[0][j], B[1][j]);
        B[2][j] = mulsub<FMA>(A[2][0], B[0][j], B[2][j]);
        B[2][j] = mulsub<FMA>(A[2][1], B[1][j], B[2][j]);
        B[2][j] = __fdiv_rn(B[2][j], A[2][2]);
        B[0][j] = mulsub<FMA>(A[0][2], B[2][j], B[0][j]);
        B[1][j] = mulsub<FMA>(A[1][2], B[2][j], B[1][j]);
        B[1][j] = __fdiv_rn(B[1][j], A[1][1]);
        B[0][j] = mulsub<FMA>(A[0][1], B[1][j], B[0][j]);
        B[0][j] = __fdiv_rn(B[0][j], A[0][0]);
    }
    o[0]=B[0][0]; o[1]=B[1][0]; o[2]=B[2][0];
    o[3]=B[0][1]; o[4]=B[1][1]; o[5]=B[2][1];
    o[6]=B[0][2]; o[7]=B[1][2]; o[8]=B[2][2];
}

template<bool FMA>
__device__ __forceinline__ float dot3(float a0,float a1,float a2,float b0,float b1,float b2){
    if (FMA) return __fmaf_rn(a2,b2, __fmaf_rn(a1,b1, __fmul_rn(a0,b0)));
    return __fadd_rn(__fadd_rn(__fmul_rn(a0,b0), __fmul_rn(a1,b1)), __fmul_rn(a2,b2));
}

// ---- K0: per-(camera, variant) matrix precompute: PRi[9] + CM[9] -> camMat ----
__global__ __launch_bounds__(64) void cam_precompute(
    const float* __restrict__ rots, const float* __restrict__ intrins,
    const float* __restrict__ post_rots, float* __restrict__ camMat)
{
    const int t = threadIdx.x;
    if (t >= 48) return;
    const int cam = t >> 1;
    const int var = t & 1;          // 0 = FMA (variant A), 1 = non-FMA (variant B)
    const float* pr = post_rots + cam*9;
    const float* ro = rots      + cam*9;
    const float* it = intrins   + cam*9;
    float PRi[9], INi[9], CM[9];
    if (var == 0) { lu_inv3x3T<true >(pr, PRi); lu_inv3x3T<true >(it, INi); }
    else          { lu_inv3x3T<false>(pr, PRi); lu_inv3x3T<false>(it, INi); }
    // comb = rots @ inv(intrins): BLAS sgemm -> FMA ascending (both variants)
    #pragma unroll
    for (int r2 = 0; r2 < 3; ++r2)
        #pragma unroll
        for (int c2 = 0; c2 < 3; ++c2)
            CM[r2*3+c2] = dot3<true>(ro[r2*3+0], ro[r2*3+1], ro[r2*3+2],
                                     INi[0*3+c2], INi[1*3+c2], INi[2*3+c2]);
    float* dst = camMat + (size_t)(cam*2 + var)*18;
    #pragma unroll
    for (int k = 0; k < 9; ++k) { dst[k] = PRi[k]; dst[9+k] = CM[k]; }
}

// Per-point geometry using precomputed PRi/CM (ops identical to R6 path)
template<bool FMA>
__device__ __forceinline__ int geom_light(
    const float* __restrict__ PRi, const float* __restrict__ CM,
    float pt0, float pt1, float pt2, float tr0, float tr1, float tr2,
    float u, float v, float dval, int b)
{
    const float p0 = __fsub_rn(u,    pt0);
    const float p1 = __fsub_rn(v,    pt1);
    const float p2 = __fsub_rn(dval, pt2);
    const float q0 = dot3<FMA>(PRi[0],PRi[1],PRi[2], p0,p1,p2);
    const float q1 = dot3<FMA>(PRi[3],PRi[4],PRi[5], p0,p1,p2);
    const float q2 = dot3<FMA>(PRi[6],PRi[7],PRi[8], p0,p1,p2);
    const float r0 = __fmul_rn(q0, q2);
    const float r1 = __fmul_rn(q1, q2);
    const float s0 = __fadd_rn(dot3<FMA>(CM[0],CM[1],CM[2], r0,r1,q2), tr0);
    const float s1 = __fadd_rn(dot3<FMA>(CM[3],CM[4],CM[5], r0,r1,q2), tr1);
    const float s2 = __fadd_rn(dot3<FMA>(CM[6],CM[7],CM[8], r0,r1,q2), tr2);
    const float CX  = -51.200000762939453f;  // f32(f32(-50.8) - f32(0.8)/2)
    const float DXf =  0.80000001192092896f; // f32(0.8)
    const float gx = __fdiv_rn(__fsub_rn(s0, CX), DXf);
    const float gy = __fdiv_rn(__fsub_rn(s1, CX), DXf);
    const float gz = __fdiv_rn(__fsub_rn(s2, -10.0f), 20.0f);
    const bool kept = (gx > -1.0f) && (gx < 128.0f) &&
                      (gy > -1.0f) && (gy < 128.0f) &&
                      (gz > -1.0f) && (gz < 1.0f);
    return kept ? (b*(NXc*NYc) + ((int)gy)*NXc + (int)gx) : -1;
}

// ---- K1: one block per (cam, wi); 16 rows x 59 depths; run-dedup scatter ----
__global__ __launch_bounds__(256) void lss_main(
    const float* __restrict__ x, const float* __restrict__ trans,
    const float* __restrict__ post_trans,
    const float* __restrict__ wd, const float* __restrict__ bd,
    const float* __restrict__ camMat, float* __restrict__ acc)
{
    const int blk = blockIdx.x;
    const int wi  = blk % FWc;
    const int cam = blk / FWc;        // 0..23
    const int b   = cam / Nc;
    const int t = threadIdx.x;
    const int wave = t >> 6, lane = t & 63;

    __shared__ float xs[16][64];
    __shared__ float yv[16][124];     // [0..58]=y then dep in-place; [59..122]=ctx
    __shared__ int   voxA[16][Dc];
    __shared__ int   voxB[16][Dc];

    // stage 1: gather the wi-column of x for all 16 rows, 64 channels
    {
        const float* xb = x + (size_t)cam*64*FHc*FWc + wi;
        for (int idx = t; idx < 1024; idx += 256) {
            const int c = idx & 63, hi = idx >> 6;
            xs[hi][c] = xb[(size_t)c*(FHc*FWc) + hi*FWc];
        }
    }
    __syncthreads();

    // stage 2: y[hi][o] = (sum_c w[o][c]*x[hi][c]) + b[o]; FMA chain ascending
    for (int idx = t; idx < 16*OCc; idx += 256) {
        const int hi = idx / OCc, o = idx - hi*OCc;
        const float* wr = wd + o*Cc;
        float a = 0.0f;
        #pragma unroll
        for (int c2 = 0; c2 < Cc; ++c2)
            a = __fmaf_rn(wr[c2], xs[hi][c2], a);
        yv[hi][o] = __fadd_rn(a, bd[o]);
    }
    __syncthreads();

    // stage 3: softmax per row (wave handles rows 4w..4w+3), dep written in place
    for (int k = 0; k < 4; ++k) {
        const int hi = (wave << 2) | k;
        float v = (lane < Dc) ? yv[hi][lane] : -INFINITY;
        float m = v;
        #pragma unroll
        for (int off = 32; off; off >>= 1) m = fmaxf(m, __shfl_xor(m, off));
        float e = (lane < Dc) ? expf(__fsub_rn(v, m)) : 0.0f;
        float s = e;
        #pragma unroll
        for (int off = 32; off; off >>= 1) s = __fadd_rn(s, __shfl_xor(s, off));
        if (lane < Dc) yv[hi][lane] = __fdiv_rn(e, s);
    }

    // stage 4: geometry for all (hi, d), both bracket variants
    {
        const float pt0 = post_trans[cam*3+0], pt1 = post_trans[cam*3+1], pt2 = post_trans[cam*3+2];
        const float tr0 = trans[cam*3+0],      tr1 = trans[cam*3+1],      tr2 = trans[cam*3+2];
        const float* M0 = camMat + (size_t)(cam*2 + 0)*18;  // FMA variant
        const float* M1 = camMat + (size_t)(cam*2 + 1)*18;  // non-FMA variant
        const float u = (float)(wi * (703.0 / 43.0));
        for (int idx = t; idx < 16*Dc; idx += 256) {
            const int hi = idx / Dc, d = idx - hi*Dc;
            const float v    = (float)(hi * 17.0);
            const float dval = (float)(1 + d);
            voxA[hi][d] = geom_light<true >(M0, M0+9, pt0,pt1,pt2, tr0,tr1,tr2, u, v, dval, b);
            voxB[hi][d] = geom_light<false>(M1, M1+9, pt0,pt1,pt2, tr0,tr1,tr2, u, v, dval, b);
        }
    }
    __syncthreads();

    // stage 5: scatter with run-length aggregation over hi (voxels repeat across rows)
    for (int d = wave; d < Dc; d += 4) {
        int runVox = -1;
        float accv = 0.0f;
        #pragma unroll
        for (int hi = 0; hi < 16; ++hi) {
            const int vA = voxA[hi][d];            // wave-uniform broadcast
            const int vB = voxB[hi][d];
            const float dw = yv[hi][d];            // dep (uniform)
            const float cx = yv[hi][59 + lane];    // ctx for this lane
            if (vA == vB) {
                if (vA >= 0) {
                    if (vA != runVox) {
                        if (runVox >= 0) atomicAdd(&acc[((size_t)runVox << 6) + lane], accv);
                        runVox = vA; accv = 0.0f;
                    }
                    accv = __fadd_rn(accv, __fmul_rn(dw, cx));
                }
            } else {
                const float hw = __fmul_rn(dw, 0.5f);
                if (vA >= 0) {
                    if (vA != runVox) {
                        if (runVox >= 0) atomicAdd(&acc[((size_t)runVox << 6) + lane], accv);
                        runVox = vA; accv = 0.0f;
                    }
                    accv = __fadd_rn(accv, __fmul_rn(hw, cx));
                }
                if (vB >= 0) atomicAdd(&acc[((size_t)vB << 6) + lane], __fmul_rn(hw, cx));
            }
        }
        if (runVox >= 0) atomicAdd(&acc[((size_t)runVox << 6) + lane], accv);
    }
}

// (b, pix, ch) -> (b, ch, pix) transpose, 64x64 tiles
__global__ __launch_bounds__(256) void lss_transpose(
    const float* __restrict__ acc, float* __restrict__ out)
{
    __shared__ float tile[64][65];
    const int blk = blockIdx.x;
    const int b = blk >> 8;
    const int pixbase = (blk & 255) * 64;
    const float* src = acc + ((size_t)b*16384 + pixbase)*64;
    const int t = threadIdx.x;
    #pragma unroll
    for (int i = 0; i < 16; ++i) {
        const int e = i*256 + t;
        tile[e & 63][e >> 6] = src[e];
    }
    __syncthreads();
    float* dst = out + (size_t)b*64*16384 + pixbase;
    #pragma unroll
    for (int i = 0; i < 16; ++i) {
        const int e = i*256 + t;
        const int c = e >> 6, p = e & 63;
        dst[(size_t)c*16384 + p] = tile[c][p];
    }
}

extern "C" void kernel_launch(void* const* d_in, const int* in_sizes, int n_in,
                              void* d_out, int out_size, void* d_ws, size_t ws_size,
                              hipStream_t stream) {
    const float* x          = (const float*)d_in[0];
    const float* rots       = (const float*)d_in[1];
    const float* trans      = (const float*)d_in[2];
    const float* intrins    = (const float*)d_in[3];
    const float* post_rots  = (const float*)d_in[4];
    const float* post_trans = (const float*)d_in[5];
    const float* wd         = (const float*)d_in[6];
    const float* bd         = (const float*)d_in[7];
    float* out = (float*)d_out;
    char* ws = (char*)d_ws;

    float* acc    = (float*)(ws + WS_ACC);
    float* camMat = (float*)(ws + WS_CAM);

    hipMemsetAsync(acc, 0, (size_t)NVOX*64*sizeof(float), stream);
    cam_precompute<<<dim3(1), dim3(64), 0, stream>>>(rots, intrins, post_rots, camMat);
    lss_main<<<dim3(NBLK), dim3(256), 0, stream>>>(
        x, trans, post_trans, wd, bd, camMat, acc);
    lss_transpose<<<dim3(Bc*256), dim3(256), 0, stream>>>(acc, out);
}

// Round 10
// 212.946 us; speedup vs baseline: 2.0688x; 1.0702x over previous
//
#include <hip/hip_runtime.h>
#include <math.h>

#define Bc 4
#define Nc 6
#define Dc 59
#define FHc 16
#define FWc 44
#define Cc 64
#define OCc 123   // D + OUT_C
#define NXc 128
#define NYc 128
#define NVOX (Bc*NXc*NYc)         // 65536
#define NBLK (Bc*Nc*FWc)          // 1056 blocks = (cam, wi)

// ws layout: acc[65536][64] f32 (16 MB), then camMat[24][2][18] f32
#define WS_ACC 0
#define WS_CAM ((size_t)16777216)

template<bool FMA>
__device__ __forceinline__ float mulsub(float a, float b, float c) {
    if (FMA) return __fmaf_rn(-a, b, c);
    return __fadd_rn(c, __fmul_rn(-a, b));
}

// numpy.linalg.inv mirror: LAPACK sgesv on the C-order buffer seen as Fortran,
// i.e. factorizes A^T (inv(A) = inv(A^T)^T). sgetf2+sgetrs, strict f32.
template<bool FMA>
__device__ __forceinline__ void lu_inv3x3T(const float* __restrict__ m, float* __restrict__ o) {
    float A[3][3] = {{m[0],m[3],m[6]},{m[1],m[4],m[7]},{m[2],m[5],m[8]}};  // A^T
    int piv0, piv1;
    {
        float a0=fabsf(A[0][0]), a1=fabsf(A[1][0]), a2=fabsf(A[2][0]);
        int p = 0; float mx = a0;
        if (a1 > mx) { mx = a1; p = 1; }
        if (a2 > mx) { mx = a2; p = 2; }
        piv0 = p;
        if (p != 0) { for (int k=0;k<3;++k){ float t=A[0][k]; A[0][k]=A[p][k]; A[p][k]=t; } }
        const float d = __fdiv_rn(1.0f, A[0][0]);
        A[1][0] = __fmul_rn(A[1][0], d);
        A[2][0] = __fmul_rn(A[2][0], d);
        #pragma unroll
        for (int i=1;i<3;++i)
            #pragma unroll
            for (int j=1;j<3;++j)
                A[i][j] = mulsub<FMA>(A[i][0], A[0][j], A[i][j]);
    }
    {
        float a1=fabsf(A[1][1]), a2=fabsf(A[2][1]);
        int p = (a2 > a1) ? 2 : 1;
        piv1 = p;
        if (p != 1) { for (int k=0;k<3;++k){ float t=A[1][k]; A[1][k]=A[p][k]; A[p][k]=t; } }
        const float d = __fdiv_rn(1.0f, A[1][1]);
        A[2][1] = __fmul_rn(A[2][1], d);
        A[2][2] = mulsub<FMA>(A[2][1], A[1][2], A[2][2]);
    }
    float B[3][3] = {{1.f,0.f,0.f},{0.f,1.f,0.f},{0.f,0.f,1.f}};
    if (piv0 != 0) { for (int k=0;k<3;++k){ float t=B[0][k]; B[0][k]=B[piv0][k]; B[piv0][k]=t; } }
    if (piv1 != 1) { for (int k=0;k<3;++k){ float t=B[1][k]; B[1][k]=B[piv1][k]; B[piv1][k]=t; } }
    #pragma unroll
    for (int j=0;j<3;++j) {
        B[1][j] = mulsub<FMA>(A[1][0], B[0][j], B[1][j]);
        B[2][j] = mulsub<FMA>(A[2][0], B[0][j], B[2][j]);
        B[2][j] = mulsub<FMA>(A[2][1], B[1][j], B[2][j]);
        B[2][j] = __fdiv_rn(B[2][j], A[2][2]);
        B[0][j] = mulsub<FMA>(A[0][2], B[2][j], B[0][j]);
        B[1][j] = mulsub<FMA>(A[1][2], B[2][j], B[1][j]);
        B[1][j] = __fdiv_rn(B[1][j], A[1][1]);
        B[0][j] = mulsub<FMA>(A[0][1], B[1][j], B[0][j]);
        B[0][j] = __fdiv_rn(B[0][j], A[0][0]);
    }
    o[0]=B[0][0]; o[1]=B[1][0]; o[2]=B[2][0];
    o[3]=B[0][1]; o[4]=B[1][1]; o[5]=B[2][1];
    o[6]=B[0][2]; o[7]=B[1][2]; o[8]=B[2][2];
}

template<bool FMA>
__device__ __forceinline__ float dot3(float a0,float a1,float a2,float b0,float b1,float b2){
    if (FMA) return __fmaf_rn(a2,b2, __fmaf_rn(a1,b1, __fmul_rn(a0,b0)));
    return __fadd_rn(__fadd_rn(__fmul_rn(a0,b0), __fmul_rn(a1,b1)), __fmul_rn(a2,b2));
}

// ---- K0: per-(camera, variant) matrix precompute: PRi[9] + CM[9] -> camMat ----
__global__ __launch_bounds__(64) void cam_precompute(
    const float* __restrict__ rots, const float* __restrict__ intrins,
    const float* __restrict__ post_rots, float* __restrict__ camMat)
{
    const int t = threadIdx.x;
    if (t >= 48) return;
    const int cam = t >> 1;
    const int var = t & 1;          // 0 = FMA (variant A), 1 = non-FMA (variant B)
    const float* pr = post_rots + cam*9;
    const float* ro = rots      + cam*9;
    const float* it = intrins   + cam*9;
    float PRi[9], INi[9], CM[9];
    if (var == 0) { lu_inv3x3T<true >(pr, PRi); lu_inv3x3T<true >(it, INi); }
    else          { lu_inv3x3T<false>(pr, PRi); lu_inv3x3T<false>(it, INi); }
    // comb = rots @ inv(intrins): BLAS sgemm -> FMA ascending (both variants)
    #pragma unroll
    for (int r2 = 0; r2 < 3; ++r2)
        #pragma unroll
        for (int c2 = 0; c2 < 3; ++c2)
            CM[r2*3+c2] = dot3<true>(ro[r2*3+0], ro[r2*3+1], ro[r2*3+2],
                                     INi[0*3+c2], INi[1*3+c2], INi[2*3+c2]);
    float* dst = camMat + (size_t)(cam*2 + var)*18;
    #pragma unroll
    for (int k = 0; k < 9; ++k) { dst[k] = PRi[k]; dst[9+k] = CM[k]; }
}

// Per-point geometry using precomputed PRi/CM (ops identical to R6 path)
template<bool FMA>
__device__ __forceinline__ int geom_light(
    const float* __restrict__ PRi, const float* __restrict__ CM,
    float pt0, float pt1, float pt2, float tr0, float tr1, float tr2,
    float u, float v, float dval, int b)
{
    const float p0 = __fsub_rn(u,    pt0);
    const float p1 = __fsub_rn(v,    pt1);
    const float p2 = __fsub_rn(dval, pt2);
    const float q0 = dot3<FMA>(PRi[0],PRi[1],PRi[2], p0,p1,p2);
    const float q1 = dot3<FMA>(PRi[3],PRi[4],PRi[5], p0,p1,p2);
    const float q2 = dot3<FMA>(PRi[6],PRi[7],PRi[8], p0,p1,p2);
    const float r0 = __fmul_rn(q0, q2);
    const float r1 = __fmul_rn(q1, q2);
    const float s0 = __fadd_rn(dot3<FMA>(CM[0],CM[1],CM[2], r0,r1,q2), tr0);
    const float s1 = __fadd_rn(dot3<FMA>(CM[3],CM[4],CM[5], r0,r1,q2), tr1);
    const float s2 = __fadd_rn(dot3<FMA>(CM[6],CM[7],CM[8], r0,r1,q2), tr2);
    const float CX  = -51.200000762939453f;  // f32(f32(-50.8) - f32(0.8)/2)
    const float DXf =  0.80000001192092896f; // f32(0.8)
    const float gx = __fdiv_rn(__fsub_rn(s0, CX), DXf);
    const float gy = __fdiv_rn(__fsub_rn(s1, CX), DXf);
    const float gz = __fdiv_rn(__fsub_rn(s2, -10.0f), 20.0f);
    const bool kept = (gx > -1.0f) && (gx < 128.0f) &&
                      (gy > -1.0f) && (gy < 128.0f) &&
                      (gz > -1.0f) && (gz < 1.0f);
    return kept ? (b*(NXc*NYc) + ((int)gy)*NXc + (int)gx) : -1;
}

// ---- K1: one block per (cam, wi); 16 rows x 59 depths; run-dedup scatter ----
// wd staged in LDS (65-pad -> conflict-free) to kill the 64-cacheline/instr
// L1 serialization that was the R7-R9 pole.
__global__ __launch_bounds__(256) void lss_main(
    const float* __restrict__ x, const float* __restrict__ trans,
    const float* __restrict__ post_trans,
    const float* __restrict__ wd, const float* __restrict__ bd,
    const float* __restrict__ camMat, float* __restrict__ acc)
{
    const int blk = blockIdx.x;
    const int wi  = blk % FWc;
    const int cam = blk / FWc;        // 0..23
    const int b   = cam / Nc;
    const int t = threadIdx.x;
    const int wave = t >> 6, lane = t & 63;

    __shared__ float wds[OCc*65];     // 31,980 B, row-padded to 65
    __shared__ float xs[16][64];
    __shared__ float yv[16][124];     // [0..58]=y then dep in-place; [59..122]=ctx
    __shared__ int   voxA[16][Dc];
    __shared__ int   voxB[16][Dc];

    // stage 0: coalesced wd -> LDS (read consecutive, write 65-padded rows)
    for (int idx = t; idx < OCc*Cc; idx += 256) {
        const int o = idx >> 6, c = idx & 63;
        wds[o*65 + c] = wd[idx];
    }
    // stage 1: gather the wi-column of x for all 16 rows, 64 channels
    {
        const float* xb = x + (size_t)cam*64*FHc*FWc + wi;
        for (int idx = t; idx < 1024; idx += 256) {
            const int c = idx & 63, hi = idx >> 6;
            xs[hi][c] = xb[(size_t)c*(FHc*FWc) + hi*FWc];
        }
    }
    __syncthreads();

    // stage 2: y[hi][o] = (sum_c w[o][c]*x[hi][c]) + b[o]; FMA chain ascending
    // LDS read wds[o*65+c2]: lanes have consecutive o -> bank (o+c2)%32 -> 2/bank, free
    for (int idx = t; idx < 16*OCc; idx += 256) {
        const int hi = idx / OCc, o = idx - hi*OCc;
        const float* wr = wds + o*65;
        float a = 0.0f;
        #pragma unroll
        for (int c2 = 0; c2 < Cc; ++c2)
            a = __fmaf_rn(wr[c2], xs[hi][c2], a);
        yv[hi][o] = __fadd_rn(a, bd[o]);
    }
    __syncthreads();

    // stage 3: softmax per row (wave handles rows 4w..4w+3), dep written in place
    for (int k = 0; k < 4; ++k) {
        const int hi = (wave << 2) | k;
        float v = (lane < Dc) ? yv[hi][lane] : -INFINITY;
        float m = v;
        #pragma unroll
        for (int off = 32; off; off >>= 1) m = fmaxf(m, __shfl_xor(m, off));
        float e = (lane < Dc) ? expf(__fsub_rn(v, m)) : 0.0f;
        float s = e;
        #pragma unroll
        for (int off = 32; off; off >>= 1) s = __fadd_rn(s, __shfl_xor(s, off));
        if (lane < Dc) yv[hi][lane] = __fdiv_rn(e, s);
    }

    // stage 4: geometry for all (hi, d), both bracket variants
    {
        const float pt0 = post_trans[cam*3+0], pt1 = post_trans[cam*3+1], pt2 = post_trans[cam*3+2];
        const float tr0 = trans[cam*3+0],      tr1 = trans[cam*3+1],      tr2 = trans[cam*3+2];
        const float* M0 = camMat + (size_t)(cam*2 + 0)*18;  // FMA variant
        const float* M1 = camMat + (size_t)(cam*2 + 1)*18;  // non-FMA variant
        const float u = (float)(wi * (703.0 / 43.0));
        for (int idx = t; idx < 16*Dc; idx += 256) {
            const int hi = idx / Dc, d = idx - hi*Dc;
            const float v    = (float)(hi * 17.0);
            const float dval = (float)(1 + d);
            voxA[hi][d] = geom_light<true >(M0, M0+9, pt0,pt1,pt2, tr0,tr1,tr2, u, v, dval, b);
            voxB[hi][d] = geom_light<false>(M1, M1+9, pt0,pt1,pt2, tr0,tr1,tr2, u, v, dval, b);
        }
    }
    __syncthreads();

    // stage 5: scatter with run-length aggregation over hi (voxels repeat across rows)
    for (int d = wave; d < Dc; d += 4) {
        int runVox = -1;
        float accv = 0.0f;
        #pragma unroll
        for (int hi = 0; hi < 16; ++hi) {
            const int vA = voxA[hi][d];            // wave-uniform broadcast
            const int vB = voxB[hi][d];
            const float dw = yv[hi][d];            // dep (uniform)
            const float cx = yv[hi][59 + lane];    // ctx for this lane
            if (vA == vB) {
                if (vA >= 0) {
                    if (vA != runVox) {
                        if (runVox >= 0) atomicAdd(&acc[((size_t)runVox << 6) + lane], accv);
                        runVox = vA; accv = 0.0f;
                    }
                    accv = __fadd_rn(accv, __fmul_rn(dw, cx));
                }
            } else {
                const float hw = __fmul_rn(dw, 0.5f);
                if (vA >= 0) {
                    if (vA != runVox) {
                        if (runVox >= 0) atomicAdd(&acc[((size_t)runVox << 6) + lane], accv);
                        runVox = vA; accv = 0.0f;
                    }
                    accv = __fadd_rn(accv, __fmul_rn(hw, cx));
                }
                if (vB >= 0) atomicAdd(&acc[((size_t)vB << 6) + lane], __fmul_rn(hw, cx));
            }
        }
        if (runVox >= 0) atomicAdd(&acc[((size_t)runVox << 6) + lane], accv);
    }
}

// (b, pix, ch) -> (b, ch, pix) transpose, 64x64 tiles
__global__ __launch_bounds__(256) void lss_transpose(
    const float* __restrict__ acc, float* __restrict__ out)
{
    __shared__ float tile[64][65];
    const int blk = blockIdx.x;
    const int b = blk >> 8;
    const int pixbase = (blk & 255) * 64;
    const float* src = acc + ((size_t)b*16384 + pixbase)*64;
    const int t = threadIdx.x;
    #pragma unroll
    for (int i = 0; i < 16; ++i) {
        const int e = i*256 + t;
        tile[e & 63][e >> 6] = src[e];
    }
    __syncthreads();
    float* dst = out + (size_t)b*64*16384 + pixbase;
    #pragma unroll
    for (int i = 0; i < 16; ++i) {
        const int e = i*256 + t;
        const int c = e >> 6, p = e & 63;
        dst[(size_t)c*16384 + p] = tile[c][p];
    }
}

extern "C" void kernel_launch(void* const* d_in, const int* in_sizes, int n_in,
                              void* d_out, int out_size, void* d_ws, size_t ws_size,
                              hipStream_t stream) {
    const float* x          = (const float*)d_in[0];
    const float* rots       = (const float*)d_in[1];
    const float* trans      = (const float*)d_in[2];
    const float* intrins    = (const float*)d_in[3];
    const float* post_rots  = (const float*)d_in[4];
    const float* post_trans = (const float*)d_in[5];
    const float* wd         = (const float*)d_in[6];
    const float* bd         = (const float*)d_in[7];
    float* out = (float*)d_out;
    char* ws = (char*)d_ws;

    float* acc    = (float*)(ws + WS_ACC);
    float* camMat = (float*)(ws + WS_CAM);

    hipMemsetAsync(acc, 0, (size_t)NVOX*64*sizeof(float), stream);
    cam_precompute<<<dim3(1), dim3(64), 0, stream>>>(rots, intrins, post_rots, camMat);
    lss_main<<<dim3(NBLK), dim3(256), 0, stream>>>(
        x, trans, post_trans, wd, bd, camMat, acc);
    lss_transpose<<<dim3(Bc*256), dim3(256), 0, stream>>>(acc, out);
}